// Round 2
// baseline (1396.832 us; speedup 1.0000x reference)
//
#include <hip/hip_runtime.h>
#include <math.h>

// RowLSTM: x(16,64,64,64) fp32, Wi(512,64,1,3), bi(512), Wh(512,128), bh(512)
// out: (16,128,64,64) fp32
//
// Phase 0: pack Wh -> Wq[(c4*512 + t)*4 + j] = Wh[t*128 + c4*4 + j]
// Phase 1: i2h = conv1d_w(x, Wi) + (bi+bh), ws layout [b][h][wt16][d][4]  (wt16 = w/4)
// Phase 2: 256 WGs = (b, 4-col tile); thread t = gate row; Wh column in 128 VGPRs;
//          per step: g = i2h + Wh_col . h  (h broadcast from LDS), nonlinearity
//          done by all 512 threads (thread = one (d, w) pair).
//
// ws floats: [0, 65536): Wq, [65536, 65536+33554432): i2h  (~128.3 MiB)

#define BB 16
#define CC 64
#define HH 64
#define WW 64
#define HID 128
#define GG 512  // 4*HID
#define KW 3

// ---------------- K0: pack Wh (512x128) -> Wq (32 x 512 x 4) ----------------
__global__ __launch_bounds__(256) void k_pack_wh(const float* __restrict__ Wh,
                                                 float* __restrict__ Wq) {
    int n = blockIdx.x * 256 + threadIdx.x;  // n = c4*512 + t, 16384 total
    int c4 = n >> 9;
    int t = n & 511;
    float4 v = *(const float4*)&Wh[t * HID + c4 * 4];
    *(float4*)&Wq[(size_t)n * 4] = v;
}

// ---------------- K1: i2h conv ----------------
// grid: B*H WGs of 512. thread t = gate row d; computes all 64 w.
__global__ __launch_bounds__(512) void k_conv(const float* __restrict__ x,
                                              const float* __restrict__ Wi,
                                              const float* __restrict__ bi,
                                              const float* __restrict__ bh,
                                              float* __restrict__ i2h) {
    __shared__ float xs[CC][72];  // row stride 288B: 16B-aligned
    const int b = blockIdx.x >> 6;
    const int h = blockIdx.x & 63;
    const int t = threadIdx.x;

    // stage x[b, :, h, :] (64x64 fp32 = 16 KB): 1024 float4 over 512 threads
    #pragma unroll
    for (int i = 0; i < 2; ++i) {
        int idx = t + i * 512;
        int c = idx >> 4;
        int w4 = (idx & 15) << 2;
        *(float4*)&xs[c][w4] =
            *(const float4*)&x[(((size_t)b * CC + c) * HH + h) * WW + w4];
    }
    __syncthreads();

    const int d = t;
    float acc[WW];
    const float bias = bi[d] + bh[d];
    #pragma unroll
    for (int w = 0; w < WW; ++w) acc[w] = bias;

    const float* wp = &Wi[(size_t)d * (CC * KW)];
    #pragma unroll 2
    for (int c = 0; c < CC; ++c) {
        const float wv0 = wp[c * 3 + 0];
        const float wv1 = wp[c * 3 + 1];
        const float wv2 = wp[c * 3 + 2];
        const float* xr = &xs[c][0];
        acc[0] += wv1 * xr[0] + wv2 * xr[1];
        #pragma unroll
        for (int w = 1; w < WW - 1; ++w)
            acc[w] += wv0 * xr[w - 1] + wv1 * xr[w] + wv2 * xr[w + 1];
        acc[WW - 1] += wv0 * xr[WW - 2] + wv1 * xr[WW - 1];
    }

    // write: [b][h][wt16][d][4]
    size_t base = (((size_t)b * HH + h) * 16) * (GG * 4) + (size_t)d * 4;
    #pragma unroll
    for (int wt = 0; wt < 16; ++wt) {
        float4 v = {acc[wt * 4], acc[wt * 4 + 1], acc[wt * 4 + 2], acc[wt * 4 + 3]};
        *(float4*)&i2h[base + (size_t)wt * (GG * 4)] = v;
    }
}

// ---------------- K2: recurrent scan over H ----------------
// grid: 256 WGs = (b, wt16). 512 threads: t = gate row; Wh col in regs.
__global__ __launch_bounds__(512) void k_lstm(const float* __restrict__ i2h,
                                              const float* __restrict__ Wq,
                                              float* __restrict__ out) {
    __shared__ float hs[HID][4];   // h state (aligned float4 rows, broadcast reads)
    __shared__ float gs[GG][5];    // gate exchange, stride 5 -> conflict-free
    const int b = blockIdx.x >> 4;
    const int wt = blockIdx.x & 15;
    const int t = threadIdx.x;

    // preload Wh row t (128 weights) into 32 float4 regs; coalesced across lanes
    float4 wreg[32];
    #pragma unroll
    for (int c4 = 0; c4 < 32; ++c4)
        wreg[c4] = *(const float4*)&Wq[((size_t)c4 * GG + t) * 4];

    const int d = t & 127;
    const int wl = t >> 7;
    hs[d][wl] = 0.f;  // 512 threads cover all 128x4 entries
    float cell = 0.f;
    __syncthreads();

    const float* ibase =
        &i2h[(((size_t)b * HH) * 16 + wt) * (GG * 4) + (size_t)t * 4];
    float4 gcur = *(const float4*)ibase;  // row 0

    for (int hr = 0; hr < HH; ++hr) {
        const int hn = (hr < HH - 1) ? hr + 1 : hr;
        const float4 gnext = *(const float4*)(ibase + (size_t)hn * (16 * GG * 4));

        float g0 = gcur.x, g1 = gcur.y, g2 = gcur.z, g3 = gcur.w;
        #pragma unroll
        for (int c4 = 0; c4 < 32; ++c4) {
            const float4 wv = wreg[c4];
            const float4 h0 = *(const float4*)&hs[c4 * 4 + 0][0];
            const float4 h1 = *(const float4*)&hs[c4 * 4 + 1][0];
            const float4 h2 = *(const float4*)&hs[c4 * 4 + 2][0];
            const float4 h3 = *(const float4*)&hs[c4 * 4 + 3][0];
            g0 += wv.x * h0.x + wv.y * h1.x + wv.z * h2.x + wv.w * h3.x;
            g1 += wv.x * h0.y + wv.y * h1.y + wv.z * h2.y + wv.w * h3.y;
            g2 += wv.x * h0.z + wv.y * h1.z + wv.z * h2.z + wv.w * h3.z;
            g3 += wv.x * h0.w + wv.y * h1.w + wv.z * h2.w + wv.w * h3.w;
        }
        gs[t][0] = g0; gs[t][1] = g1; gs[t][2] = g2; gs[t][3] = g3;
        __syncthreads();

        // nonlinearity: thread = (d, wl) pair
        const float ig = gs[d][wl];
        const float fg = gs[d + HID][wl];
        const float og = gs[d + 2 * HID][wl];
        const float gv = gs[d + 3 * HID][wl];
        const float si = 1.f / (1.f + __expf(-ig));
        const float sf = 1.f / (1.f + __expf(-fg));
        const float so = 1.f / (1.f + __expf(-og));
        // tanh(x) = 1 - 2/(exp(2x)+1): NaN-free at +/-inf
        const float tg = 1.f - 2.f / (__expf(2.f * gv) + 1.f);
        cell = sf * cell + si * tg;
        const float th = 1.f - 2.f / (__expf(2.f * cell) + 1.f);
        const float hv = so * th;
        hs[d][wl] = hv;
        out[(((size_t)b * HID + d) * HH + hr) * WW + (size_t)wt * 4 + wl] = hv;
        __syncthreads();

        gcur = gnext;
    }
}

extern "C" void kernel_launch(void* const* d_in, const int* in_sizes, int n_in,
                              void* d_out, int out_size, void* d_ws, size_t ws_size,
                              hipStream_t stream) {
    const float* x  = (const float*)d_in[0];
    const float* Wi = (const float*)d_in[1];
    const float* bi = (const float*)d_in[2];
    const float* Wh = (const float*)d_in[3];
    const float* bh = (const float*)d_in[4];
    float* out = (float*)d_out;
    float* ws  = (float*)d_ws;

    float* Wq  = ws;          // 65536 floats
    float* i2h = ws + 65536;  // 33554432 floats

    hipLaunchKernelGGL(k_pack_wh, dim3(64), dim3(256), 0, stream, Wh, Wq);
    hipLaunchKernelGGL(k_conv, dim3(BB * HH), dim3(512), 0, stream, x, Wi, bi, bh, i2h);
    hipLaunchKernelGGL(k_lstm, dim3(BB * 16), dim3(512), 0, stream, i2h, Wq, out);
}

// Round 5
// 448.187 us; speedup vs baseline: 3.1166x; 3.1166x over previous
//
#include <hip/hip_runtime.h>
#include <math.h>

// RowLSTM: x(16,64,64,64) fp32, Wi(512,64,1,3), bi(512), Wh(512,128), bh(512)
// out: (16,128,64,64) fp32
//
// K0 k_pack:  Wip[k][d] = Wi[d][k]  (k = c*3+kw, 192 x 512) -- lane-coalesced conv weights
// K1 k_conv:  i2h[b][h][wq][col][512] = conv + bi + bh  (wq = w>>4, col = w&15)
// K2 k_lstm:  64 WGs = (b, wq); 8 waves; recurrent GEMM via mfma_f32_16x16x32_bf16
//             with 3-term bf16 split (whi*hhi + whi*hlo + wlo*hhi), acc init = i2h.
//
// ws floats: [0, 33554432): i2h, [33554432, +98304): Wip

#define BB 16
#define CC 64
#define HH 64
#define WW 64
#define HID 128
#define GG 512  // 4*HID
#define KW 3

typedef __attribute__((ext_vector_type(8))) short short8;
typedef __attribute__((ext_vector_type(4))) float f32x4;

__device__ inline unsigned short f32_to_bf16_rne(float f) {
    unsigned int u = __float_as_uint(f);
    unsigned int r = (u + 0x7fffu + ((u >> 16) & 1u)) >> 16;
    return (unsigned short)r;
}
__device__ inline float bf16_to_f32(unsigned short s) {
    return __uint_as_float(((unsigned int)s) << 16);
}

// ---------------- K0: pack conv weights ----------------
__global__ __launch_bounds__(256) void k_pack(const float* __restrict__ Wi,
                                              float* __restrict__ Wip) {
    int n = blockIdx.x * 256 + threadIdx.x;  // n = k*512 + d, 98304 total
    int k = n >> 9;
    int d = n & 511;
    Wip[n] = Wi[(size_t)d * (CC * KW) + k];
}

// ---------------- K1: i2h conv ----------------
// grid: B*H WGs of 512. thread t = gate row d; computes all 64 w.
__global__ __launch_bounds__(512) void k_conv(const float* __restrict__ x,
                                              const float* __restrict__ Wip,
                                              const float* __restrict__ bi,
                                              const float* __restrict__ bh,
                                              float* __restrict__ i2h) {
    __shared__ float xs[CC][72];
    const int b = blockIdx.x >> 6;
    const int h = blockIdx.x & 63;
    const int t = threadIdx.x;

    #pragma unroll
    for (int i = 0; i < 2; ++i) {
        int idx = t + i * 512;
        int c = idx >> 4;
        int w4 = (idx & 15) << 2;
        *(float4*)&xs[c][w4] =
            *(const float4*)&x[(((size_t)b * CC + c) * HH + h) * WW + w4];
    }
    __syncthreads();

    const int d = t;
    float acc[WW];
    const float bias = bi[d] + bh[d];
    #pragma unroll
    for (int w = 0; w < WW; ++w) acc[w] = bias;

    #pragma unroll 2
    for (int c = 0; c < CC; ++c) {
        const float wv0 = Wip[(size_t)(c * 3 + 0) * GG + d];  // coalesced across lanes
        const float wv1 = Wip[(size_t)(c * 3 + 1) * GG + d];
        const float wv2 = Wip[(size_t)(c * 3 + 2) * GG + d];
        const float* xr = &xs[c][0];
        acc[0] += wv1 * xr[0] + wv2 * xr[1];
        #pragma unroll
        for (int w = 1; w < WW - 1; ++w)
            acc[w] += wv0 * xr[w - 1] + wv1 * xr[w] + wv2 * xr[w + 1];
        acc[WW - 1] += wv0 * xr[WW - 2] + wv1 * xr[WW - 1];
    }

    // i2h[b][h][wq][col][512], coalesced dword stores (lanes = consecutive d)
    const size_t bh4 = ((size_t)b * HH + h) * 4;
    #pragma unroll
    for (int w = 0; w < WW; ++w) {
        i2h[((bh4 + (w >> 4)) * 16 + (w & 15)) * GG + d] = acc[w];
    }
}

// ---------------- K2: recurrent scan via MFMA ----------------
// 64 WGs = (b, wq). 512 threads = 8 waves; wave wv owns gate rows 64*wv..64*wv+63.
__global__ __launch_bounds__(512, 2) void k_lstm(const float* __restrict__ i2h,
                                                 const float* __restrict__ Wh,
                                                 float* __restrict__ out) {
    __shared__ unsigned short hTh[16 * 136];  // h hi, [col][c], pad 136 (16B-aligned rows)
    __shared__ unsigned short hTl[16 * 136];  // h lo
    __shared__ float gsm[GG * 17];            // gate exchange, stride 17

    const int b = blockIdx.x >> 2;
    const int wq = blockIdx.x & 3;
    const int t = threadIdx.x;
    const int lane = t & 63;
    const int wv = t >> 6;
    const int lr = lane & 15;  // A row-in-frag / B,C col
    const int lq = lane >> 4;  // k-group / C row-group

    // ---- preload A fragments: Wh rows (bf16 hi/lo), 128 VGPRs ----
    short8 ahi[4][4], alo[4][4];
    #pragma unroll
    for (int mf = 0; mf < 4; ++mf) {
        #pragma unroll
        for (int kf = 0; kf < 4; ++kf) {
            const int row = wv * 64 + mf * 16 + lr;
            const int k0 = kf * 32 + lq * 8;
            const float* src = &Wh[(size_t)row * HID + k0];
            short8 h8, l8;
            #pragma unroll
            for (int j = 0; j < 8; ++j) {
                float v = src[j];
                unsigned short hb = f32_to_bf16_rne(v);
                unsigned short lb = f32_to_bf16_rne(v - bf16_to_f32(hb));
                h8[j] = (short)hb;
                l8[j] = (short)lb;
            }
            ahi[mf][kf] = h8;
            alo[mf][kf] = l8;
        }
    }

    // zero h state
    for (int i = t; i < 16 * 136; i += 512) { hTh[i] = 0; hTl[i] = 0; }

    // nonlinearity ownership: thread = (d, 4 cols)
    const int d = t >> 2;
    const int cg = t & 3;
    float cell[4] = {0.f, 0.f, 0.f, 0.f};

    // first i2h row
    const float* ib0 = &i2h[((((size_t)b * HH) * 4 + wq) * 16 + lr) * GG + wv * 64 + lq * 4];
    const size_t rowstride = (size_t)4 * 16 * GG;  // one hr step
    f32x4 gbuf[4];
    #pragma unroll
    for (int mf = 0; mf < 4; ++mf) gbuf[mf] = *(const f32x4*)(ib0 + mf * 16);

    __syncthreads();

    for (int hr = 0; hr < HH; ++hr) {
        f32x4 acc[4];
        #pragma unroll
        for (int mf = 0; mf < 4; ++mf) acc[mf] = gbuf[mf];

        // prefetch next row's i2h
        const int hn = (hr < HH - 1) ? hr + 1 : hr;
        const float* ibn = ib0 + (size_t)hn * rowstride;
        #pragma unroll
        for (int mf = 0; mf < 4; ++mf) gbuf[mf] = *(const f32x4*)(ibn + mf * 16);

        // GEMM: gates += Wh * h   (3-term bf16 split)
        #pragma unroll
        for (int kf = 0; kf < 4; ++kf) {
            const int baddr = lr * 136 + kf * 32 + lq * 8;
            const short8 bhf = *(const short8*)&hTh[baddr];
            const short8 blf = *(const short8*)&hTl[baddr];
            #pragma unroll
            for (int mf = 0; mf < 4; ++mf)
                acc[mf] = __builtin_amdgcn_mfma_f32_16x16x32_bf16(alo[mf][kf], bhf, acc[mf], 0, 0, 0);
            #pragma unroll
            for (int mf = 0; mf < 4; ++mf)
                acc[mf] = __builtin_amdgcn_mfma_f32_16x16x32_bf16(ahi[mf][kf], blf, acc[mf], 0, 0, 0);
            #pragma unroll
            for (int mf = 0; mf < 4; ++mf)
                acc[mf] = __builtin_amdgcn_mfma_f32_16x16x32_bf16(ahi[mf][kf], bhf, acc[mf], 0, 0, 0);
        }

        // scatter gates to LDS
        #pragma unroll
        for (int mf = 0; mf < 4; ++mf) {
            #pragma unroll
            for (int r = 0; r < 4; ++r)
                gsm[(wv * 64 + mf * 16 + lq * 4 + r) * 17 + lr] = acc[mf][r];
        }
        __syncthreads();

        // nonlinearity: thread (d, cols cg*4..cg*4+3)
        f32x4 ov;
        #pragma unroll
        for (int u = 0; u < 4; ++u) {
            const int col = cg * 4 + u;
            const float ig = gsm[(d)*17 + col];
            const float fg = gsm[(d + HID) * 17 + col];
            const float og = gsm[(d + 2 * HID) * 17 + col];
            const float gv = gsm[(d + 3 * HID) * 17 + col];
            const float si = 1.f / (1.f + __expf(-ig));
            const float sf = 1.f / (1.f + __expf(-fg));
            const float so = 1.f / (1.f + __expf(-og));
            const float tg = 1.f - 2.f / (__expf(2.f * gv) + 1.f);
            cell[u] = sf * cell[u] + si * tg;
            const float th = 1.f - 2.f / (__expf(2.f * cell[u]) + 1.f);
            const float hv = so * th;
            ov[u] = hv;
            const unsigned short hb = f32_to_bf16_rne(hv);
            hTh[col * 136 + d] = hb;
            hTl[col * 136 + d] = f32_to_bf16_rne(hv - bf16_to_f32(hb));
        }
        *(f32x4*)&out[(((size_t)b * HID + d) * HH + hr) * WW + wq * 16 + cg * 4] = ov;
        __syncthreads();
    }
}

extern "C" void kernel_launch(void* const* d_in, const int* in_sizes, int n_in,
                              void* d_out, int out_size, void* d_ws, size_t ws_size,
                              hipStream_t stream) {
    const float* x  = (const float*)d_in[0];
    const float* Wi = (const float*)d_in[1];
    const float* bi = (const float*)d_in[2];
    const float* Wh = (const float*)d_in[3];
    const float* bh = (const float*)d_in[4];
    float* out = (float*)d_out;
    float* ws  = (float*)d_ws;

    float* i2h = ws;                  // 33554432 floats
    float* Wip = ws + 33554432;       // 98304 floats

    hipLaunchKernelGGL(k_pack, dim3(384), dim3(256), 0, stream, Wi, Wip);
    hipLaunchKernelGGL(k_conv, dim3(BB * HH), dim3(512), 0, stream, x, Wip, bi, bh, i2h);
    hipLaunchKernelGGL(k_lstm, dim3(BB * 4), dim3(512), 0, stream, i2h, Wh, out);
}

// Round 6
// 279.275 us; speedup vs baseline: 5.0016x; 1.6048x over previous
//
#include <hip/hip_runtime.h>
#include <math.h>

// RowLSTM: x(16,64,64,64) fp32, Wi(512,64,1,3), bi(512), Wh(512,128), bh(512)
// out: (16,128,64,64) fp32
//
// Gate-row permutation: slot(gate,d) = (d>>4)*64 + gate*16 + (d&15).
// Wave wv of k_lstm owns d in [16wv,16wv+16); its 4 M-frags = the 4 gates of those d
// -> nonlinearity entirely in-register, 1 barrier/step, h double-buffered in LDS.
//
// K0 k_pack: Wi -> bf16 hi/lo, A-frag order Wip[kw][slot][c]
// K1 k_conv: MFMA conv as 3 shifted K=64 GEMMs; xT[w][c] bf16 hi/lo in LDS (halo=0).
//            i2h[b][h][wq][col][slot] = conv + bi + bh  (fp32)
// K2 k_lstm: 64 WGs = (b,wq); 8 waves; 3-term bf16-split MFMA; in-reg gates.
//
// ws: [0, 33554432) fp32 i2h; then Wiphi (98304 u16), Wiplo (98304 u16)

#define BB 16
#define CC 64
#define HH 64
#define WW 64
#define HID 128
#define GG 512
#define KW 3

typedef __attribute__((ext_vector_type(8))) short short8;
typedef __attribute__((ext_vector_type(4))) float f32x4;
typedef __attribute__((ext_vector_type(4))) unsigned short u16x4;

__device__ inline unsigned short f32_to_bf16_rne(float f) {
    unsigned int u = __float_as_uint(f);
    unsigned int r = (u + 0x7fffu + ((u >> 16) & 1u)) >> 16;
    return (unsigned short)r;
}
__device__ inline float bf16_to_f32(unsigned short s) {
    return __uint_as_float(((unsigned int)s) << 16);
}

// ---------------- K0: pack Wi -> bf16 hi/lo, [kw][slot][c] ----------------
__global__ __launch_bounds__(256) void k_pack(const float* __restrict__ Wi,
                                              unsigned short* __restrict__ Wiphi,
                                              unsigned short* __restrict__ Wiplo) {
    int n = blockIdx.x * 256 + threadIdx.x;  // n = (kw*512 + s)*64 + c, 98304
    int kw = n >> 15;
    int rem = n & 32767;
    int s = rem >> 6;
    int c = rem & 63;
    // slot s = (d>>4)*64 + gate*16 + (d&15)  ->  gd = gate*128 + d
    int gd = ((s >> 4) & 3) * 128 + (s >> 6) * 16 + (s & 15);
    float v = Wi[(size_t)gd * (CC * KW) + c * 3 + kw];
    unsigned short hb = f32_to_bf16_rne(v);
    Wiphi[n] = hb;
    Wiplo[n] = f32_to_bf16_rne(v - bf16_to_f32(hb));
}

// ---------------- K1: conv via MFMA ----------------
// 1024 WGs = (b,h); 512 thr = 8 waves. Wave wv -> d in [16wv,16wv+16), all 64 cols.
__global__ __launch_bounds__(512, 2) void k_conv(const float* __restrict__ x,
                                                 const unsigned short* __restrict__ Wiphi,
                                                 const unsigned short* __restrict__ Wiplo,
                                                 const float* __restrict__ bi,
                                                 const float* __restrict__ bh,
                                                 float* __restrict__ i2h) {
    __shared__ unsigned short xhiT[66 * 72];  // xT[wi][c] = x[c][wi-1]; rows 0,65 = 0 pad
    __shared__ unsigned short xloT[66 * 72];  // 72-short stride: 144B, 16B-aligned rows

    const int b = blockIdx.x >> 6;
    const int h = blockIdx.x & 63;
    const int t = threadIdx.x;
    const int lane = t & 63;
    const int wv = t >> 6;
    const int lr = lane & 15;
    const int lq = lane >> 4;

    // stage x[b,:,h,:] transposed to LDS as bf16 hi/lo. thread: c = t>>3, w0=(t&7)*8
    {
        const int c = t >> 3;
        const int w0 = (t & 7) * 8;
        const float* xp = &x[(((size_t)b * CC + c) * HH + h) * WW + w0];
        float4 v0 = *(const float4*)xp;
        float4 v1 = *(const float4*)(xp + 4);
        float vv[8] = {v0.x, v0.y, v0.z, v0.w, v1.x, v1.y, v1.z, v1.w};
        #pragma unroll
        for (int i = 0; i < 8; ++i) {
            unsigned short hb = f32_to_bf16_rne(vv[i]);
            xhiT[(w0 + i + 1) * 72 + c] = hb;
            xloT[(w0 + i + 1) * 72 + c] = f32_to_bf16_rne(vv[i] - bf16_to_f32(hb));
        }
        if (t < 64) { xhiT[t] = 0; xloT[t] = 0; xhiT[65 * 72 + t] = 0; xloT[65 * 72 + t] = 0; }
    }

    // acc init = bias (gate mf, d = wv*16 + lq*4 + r)
    f32x4 acc[4][4];  // [mf][nf]
    #pragma unroll
    for (int mf = 0; mf < 4; ++mf) {
        #pragma unroll
        for (int r = 0; r < 4; ++r) {
            const int gd = mf * 128 + wv * 16 + lq * 4 + r;
            const float bias = bi[gd] + bh[gd];
            #pragma unroll
            for (int nf = 0; nf < 4; ++nf) acc[mf][nf][r] = bias;
        }
    }
    __syncthreads();

    // 3 taps x 2 k-frags; 3-term bf16 split
    #pragma unroll
    for (int kw = 0; kw < 3; ++kw) {
        #pragma unroll
        for (int kf = 0; kf < 2; ++kf) {
            short8 Ah[4], Al[4];
            #pragma unroll
            for (int mf = 0; mf < 4; ++mf) {
                const size_t abase =
                    ((size_t)(kw * 512) + wv * 64 + mf * 16 + lr) * 64 + kf * 32 + lq * 8;
                Ah[mf] = *(const short8*)&Wiphi[abase];
                Al[mf] = *(const short8*)&Wiplo[abase];
            }
            short8 Bh[4], Bl[4];
            #pragma unroll
            for (int nf = 0; nf < 4; ++nf) {
                const int baddr = (nf * 16 + lr + kw) * 72 + kf * 32 + lq * 8;
                Bh[nf] = *(const short8*)&xhiT[baddr];
                Bl[nf] = *(const short8*)&xloT[baddr];
            }
            #pragma unroll
            for (int mf = 0; mf < 4; ++mf) {
                #pragma unroll
                for (int nf = 0; nf < 4; ++nf) {
                    acc[mf][nf] = __builtin_amdgcn_mfma_f32_16x16x32_bf16(Al[mf], Bh[nf], acc[mf][nf], 0, 0, 0);
                    acc[mf][nf] = __builtin_amdgcn_mfma_f32_16x16x32_bf16(Ah[mf], Bl[nf], acc[mf][nf], 0, 0, 0);
                    acc[mf][nf] = __builtin_amdgcn_mfma_f32_16x16x32_bf16(Ah[mf], Bh[nf], acc[mf][nf], 0, 0, 0);
                }
            }
        }
    }

    // store: i2h[((b*64+h)*4 + nf)*16 + lr][slot], slot base = wv*64 + mf*16 + lq*4
    const size_t obase0 = (((size_t)b * HH + h) * 4);
    #pragma unroll
    for (int nf = 0; nf < 4; ++nf) {
        #pragma unroll
        for (int mf = 0; mf < 4; ++mf) {
            const size_t idx = ((obase0 + nf) * 16 + lr) * GG + wv * 64 + mf * 16 + lq * 4;
            *(f32x4*)&i2h[idx] = acc[mf][nf];
        }
    }
}

// ---------------- K2: recurrent scan, in-register gates ----------------
// 64 WGs = (b,wq); 8 waves; wave wv -> d in [16wv,16wv+16), cols wq*16..+15.
__global__ __launch_bounds__(512, 2) void k_lstm(const float* __restrict__ i2h,
                                                 const float* __restrict__ Wh,
                                                 float* __restrict__ out) {
    __shared__ unsigned short hTh[2 * 16 * 136];  // [buf][col][d], 272B rows
    __shared__ unsigned short hTl[2 * 16 * 136];

    const int b = blockIdx.x >> 2;
    const int wq = blockIdx.x & 3;
    const int t = threadIdx.x;
    const int lane = t & 63;
    const int wv = t >> 6;
    const int lr = lane & 15;
    const int lq = lane >> 4;

    // A fragments: Wh row gd = mf*128 + wv*16 + lr (gate-permuted), bf16 hi/lo
    short8 ahi[4][4], alo[4][4];
    #pragma unroll
    for (int mf = 0; mf < 4; ++mf) {
        #pragma unroll
        for (int kf = 0; kf < 4; ++kf) {
            const int gd = mf * 128 + wv * 16 + lr;
            const float* src = &Wh[(size_t)gd * HID + kf * 32 + lq * 8];
            short8 h8, l8;
            #pragma unroll
            for (int j = 0; j < 8; ++j) {
                float v = src[j];
                unsigned short hb = f32_to_bf16_rne(v);
                h8[j] = (short)hb;
                l8[j] = (short)f32_to_bf16_rne(v - bf16_to_f32(hb));
            }
            ahi[mf][kf] = h8;
            alo[mf][kf] = l8;
        }
    }

    for (int i = t; i < 16 * 136; i += 512) { hTh[i] = 0; hTl[i] = 0; }  // buf 0

    float cell[4] = {0.f, 0.f, 0.f, 0.f};

    const float* ib0 = &i2h[((((size_t)b * HH) * 4 + wq) * 16 + lr) * GG + wv * 64 + lq * 4];
    const size_t rowstride = (size_t)4 * 16 * GG;
    f32x4 gbuf[4];
    #pragma unroll
    for (int mf = 0; mf < 4; ++mf) gbuf[mf] = *(const f32x4*)(ib0 + mf * 16);

    __syncthreads();

    int cur = 0;
    for (int hr = 0; hr < HH; ++hr) {
        f32x4 acc[4];
        #pragma unroll
        for (int mf = 0; mf < 4; ++mf) acc[mf] = gbuf[mf];

        // prefetch next row's i2h (consumed next iter; covered by MFMA+nonlin)
        const int hn = (hr < HH - 1) ? hr + 1 : hr;
        const float* ibn = ib0 + (size_t)hn * rowstride;
        #pragma unroll
        for (int mf = 0; mf < 4; ++mf) gbuf[mf] = *(const f32x4*)(ibn + mf * 16);

        // gates += Wh * h (3-term split); B from hT[cur]
        #pragma unroll
        for (int kf = 0; kf < 4; ++kf) {
            const int baddr = (cur * 16 + lr) * 136 + kf * 32 + lq * 8;
            const short8 bhf = *(const short8*)&hTh[baddr];
            const short8 blf = *(const short8*)&hTl[baddr];
            #pragma unroll
            for (int mf = 0; mf < 4; ++mf)
                acc[mf] = __builtin_amdgcn_mfma_f32_16x16x32_bf16(alo[mf][kf], bhf, acc[mf], 0, 0, 0);
            #pragma unroll
            for (int mf = 0; mf < 4; ++mf)
                acc[mf] = __builtin_amdgcn_mfma_f32_16x16x32_bf16(ahi[mf][kf], blf, acc[mf], 0, 0, 0);
            #pragma unroll
            for (int mf = 0; mf < 4; ++mf)
                acc[mf] = __builtin_amdgcn_mfma_f32_16x16x32_bf16(ahi[mf][kf], bhf, acc[mf], 0, 0, 0);
        }

        // in-register nonlinearity: lane owns (d = wv*16 + lq*4 + r, col = lr)
        const int nxt = cur ^ 1;
        u16x4 hb4, lb4;
        #pragma unroll
        for (int r = 0; r < 4; ++r) {
            const float ig = acc[0][r];
            const float fg = acc[1][r];
            const float og = acc[2][r];
            const float gv = acc[3][r];
            const float si = 1.f / (1.f + __expf(-ig));
            const float sf = 1.f / (1.f + __expf(-fg));
            const float so = 1.f / (1.f + __expf(-og));
            const float tg = 1.f - 2.f / (__expf(2.f * gv) + 1.f);
            cell[r] = sf * cell[r] + si * tg;
            const float th = 1.f - 2.f / (__expf(2.f * cell[r]) + 1.f);
            const float hv = so * th;
            const int d = wv * 16 + lq * 4 + r;
            out[(((size_t)b * HID + d) * HH + hr) * WW + wq * 16 + lr] = hv;
            const unsigned short hb = f32_to_bf16_rne(hv);
            hb4[r] = hb;
            lb4[r] = f32_to_bf16_rne(hv - bf16_to_f32(hb));
        }
        // h-state write: 8B contiguous (d = wv*16 + lq*4 .. +3)
        const int haddr = (nxt * 16 + lr) * 136 + wv * 16 + lq * 4;
        *(u16x4*)&hTh[haddr] = hb4;
        *(u16x4*)&hTl[haddr] = lb4;

        __syncthreads();
        cur = nxt;
    }
}

extern "C" void kernel_launch(void* const* d_in, const int* in_sizes, int n_in,
                              void* d_out, int out_size, void* d_ws, size_t ws_size,
                              hipStream_t stream) {
    const float* x  = (const float*)d_in[0];
    const float* Wi = (const float*)d_in[1];
    const float* bi = (const float*)d_in[2];
    const float* Wh = (const float*)d_in[3];
    const float* bh = (const float*)d_in[4];
    float* out = (float*)d_out;
    float* ws  = (float*)d_ws;

    float* i2h = ws;  // 33554432 floats
    unsigned short* Wiphi = (unsigned short*)(ws + 33554432);  // 98304 u16
    unsigned short* Wiplo = Wiphi + 98304;

    hipLaunchKernelGGL(k_pack, dim3(384), dim3(256), 0, stream, Wi, Wiphi, Wiplo);
    hipLaunchKernelGGL(k_conv, dim3(BB * HH), dim3(512), 0, stream, x, Wiphi, Wiplo, bi, bh, i2h);
    hipLaunchKernelGGL(k_lstm, dim3(BB * 4), dim3(512), 0, stream, i2h, Wh, out);
}